// Round 3
// baseline (248.106 us; speedup 1.0000x reference)
//
#include <hip/hip_runtime.h>
#include <math.h>

#define NBINS 8
#define IMG 224
#define HC 28                 // cells per side
#define OUTPER (HC*HC*NBINS)  // 6272
#define BATCH 256
#define PL (IMG*IMG)          // floats per plane
#define BANDR 34              // gray rows per block band (32 + 2 halo)
#define LDSW 232              // LDS row stride in floats; data at cols 4..227,
                              // col 3 = image col -1 (zero), col 228 = col 224 (zero)
#define NF4 (BANDR*56)        // 1904 float4s per band fill

// pair-swap within quads (lane 2j <-> 2j+1): quad_perm(1,0,3,2) = 0xB1.
__device__ __forceinline__ float dpp_swap1(float x) {
    return __int_as_float(__builtin_amdgcn_update_dpp(
        0, __float_as_int(x), 0xB1, 0xF, 0xF, false));
}

// ---------------- main kernel: block = 4 waves = 4 cell-rows of one image --
// Theory: prior rounds were latency-bound at ~1 TB/s read BW because each
// wave issued 256-896B touches into 3 planes at 196KB stride (thousands of
// DRAM micro-streams -> page thrash; L3 is swept by the 616MB ws poison each
// iter so reads are HBM-cold). This version loads a CONTIGUOUS 34-row band
// per block (3 planes, 4KB sequential sweeps), grays into LDS once, then
// computes from LDS. 31.6KB LDS -> 5 blocks/CU = 20 waves/CU; VGPRs free.
__global__ __launch_bounds__(256) void hog_main_kernel(
    const float* __restrict__ x, const float* __restrict__ gauss,
    float* __restrict__ out, float* __restrict__ partial)
{
    __shared__ float gs[BANDR * LDSW];    // 31.6 KB gray band

    const int tid = threadIdx.x;
    const int bc  = blockIdx.x;           // 0..1791
    const int b   = bc / 7;
    const int blk = bc - b * 7;           // band 0..6 within image
    const int rowTop = blk * 32 - 1;      // first gray row of band (may be -1)
    const float* xb = x + (size_t)b * 3 * PL;

    // zero halo columns (image col -1 / col 224) for all band rows
    if (tid < 2 * BANDR) {
        int r = tid >> 1;
        gs[r * LDSW + ((tid & 1) ? 228 : 3)] = 0.f;
    }

    // ---- cooperative band fill: branchless, clamped rows, all loads
    //      independent (deep MLP), 4KB-contiguous per plane per step ----
    auto fill_one = [&](int i) {
        int r    = i / 56;                // band row 0..33
        int c4   = (i - r * 56) * 4;      // col 0..220
        int grow = rowTop + r;
        int gc   = grow < 0 ? 0 : (grow > IMG - 1 ? IMG - 1 : grow);
        const float* p = xb + gc * IMG + c4;
        float4 R = *(const float4*)(p);
        float4 G = *(const float4*)(p + PL);
        float4 B = *(const float4*)(p + 2 * PL);
        bool z = (grow != gc);            // out-of-image row -> zero pad
        float4 g;
        g.x = z ? 0.f : 0.2989f * R.x + 0.587f * G.x + 0.114f * B.x;
        g.y = z ? 0.f : 0.2989f * R.y + 0.587f * G.y + 0.114f * B.y;
        g.z = z ? 0.f : 0.2989f * R.z + 0.587f * G.z + 0.114f * B.z;
        g.w = z ? 0.f : 0.2989f * R.w + 0.587f * G.w + 0.114f * B.w;
        *(float4*)&gs[r * LDSW + c4 + 4] = g;
    };
    #pragma unroll
    for (int it = 0; it < 7; ++it) fill_one(tid + it * 256);
    if (tid < NF4 - 7 * 256) fill_one(tid + 7 * 256);   // tail: 112 live

    __syncthreads();

    // ---- compute phase: wave wv owns cell-row cr, lane i owns cols 4i..4i+3
    const int wv   = tid >> 6;
    const int lane = tid & 63;
    const int cr   = blk * 4 + wv;        // cell row 0..27
    const int li   = lane < 55 ? lane : 55;   // dead lanes read safe addrs

    float4 v[10]; float hl[10], hr[10];
    const float* base = gs + (wv * 8) * LDSW + li * 4 + 4;
    #pragma unroll
    for (int j = 0; j < 10; ++j) {
        v[j]  = *(const float4*)(base + j * LDSW);
        hl[j] = base[j * LDSW - 1];       // image col 4*li - 1 (zero at col -1)
        hr[j] = base[j * LDSW + 4];       // image col 4*li + 4 (zero at col 224)
    }

    // separable gauss: w(sr, col) = EROW[sr] * ECOL[col&7]; ECOL symmetric
    const float E0 = 0.0021874911f, E1 = 0.043936934f,
                E2 = 0.32465247f,   E3 = 0.88249690f;
    const bool odd = (lane & 1);
    const float ew0 = odd ? E3 : E0, ew1 = odd ? E2 : E1,
                ew2 = odd ? E1 : E2, ew3 = odd ? E0 : E3;
    const float EROW[8] = { E0, E1, E2, E3, E3, E2, E1, E0 };

    float h[8];
    #pragma unroll
    for (int k = 0; k < 8; ++k) h[k] = 0.f;

    auto pix = [&](float gx, float gy, float w) {
        float mag = __builtin_amdgcn_sqrtf(gx * gx + gy * gy + 1e-6f);
        float ax = fabsf(gx), ay = fabsf(gy);
        // exact-octant bin == floor(mod(atan2(gy,gx),2pi)/(pi/4));
        // boundary semantics verified in prior rounds — do not touch
        int bin;
        if (gy > 0.f)       bin = (gx > 0.f)  ? ((gy < gx) ? 0 : 1)
                                : (gx == 0.f) ? 2 : ((ay > ax) ? 2 : 3);
        else if (gy == 0.f) bin = (gx < 0.f) ? 4 : 0;
        else                bin = (gx < 0.f)  ? ((ay < ax) ? 4 : 5)
                                : (gx == 0.f) ? 6 : ((ay > ax) ? 6 : 7);
        float wm = w * mag;
        #pragma unroll
        for (int k = 0; k < 8; ++k) h[k] += (bin == k) ? wm : 0.f;
    };

    #pragma unroll
    for (int sr = 0; sr < 8; ++sr) {
        float4 t = v[sr], m = v[sr + 1], bt = v[sr + 2];
        float tl = hl[sr], ml = hl[sr + 1], bl = hl[sr + 2];
        float tr = hr[sr], mr = hr[sr + 1], br = hr[sr + 2];
        // vertical smooth s / diff d at cols -1..4
        float sm1 = tl  + 2.f * ml  + bl;
        float s0  = t.x + 2.f * m.x + bt.x;
        float s1  = t.y + 2.f * m.y + bt.y;
        float s2  = t.z + 2.f * m.z + bt.z;
        float s3  = t.w + 2.f * m.w + bt.w;
        float s4  = tr  + 2.f * mr  + br;
        float dm1 = bl  - tl;
        float d0  = bt.x - t.x, d1 = bt.y - t.y,
              d2  = bt.z - t.z, d3 = bt.w - t.w;
        float d4  = br - tr;

        float gx0 = s1 - sm1, gx1 = s2 - s0, gx2 = s3 - s1, gx3 = s4 - s2;
        float gy0 = dm1 + 2.f * d0 + d1, gy1 = d0 + 2.f * d1 + d2,
              gy2 = d1  + 2.f * d2 + d3, gy3 = d2 + 2.f * d3 + d4;

        float er = EROW[sr];
        pix(gx0, gy0, er * ew0);
        pix(gx1, gy1, er * ew1);
        pix(gx2, gy2, er * ew2);
        pix(gx3, gy3, er * ew3);
    }

    // cell = lanes (2j, 2j+1): pair-reduce via DPP (VALU, no DS pipe)
    #pragma unroll
    for (int k = 0; k < 8; ++k) h[k] += dpp_swap1(h[k]);

    float ssq = 0.f;
    if (lane < 56) {
        float4 st = odd ? make_float4(h[4], h[5], h[6], h[7])
                        : make_float4(h[0], h[1], h[2], h[3]);
        *(float4*)(out + (size_t)b * OUTPER + (size_t)cr * IMG + 4 * lane) = st;
        ssq = st.x * st.x + st.y * st.y + st.z * st.z + st.w * st.w;
    }

    // per-(image, cell-row) sumsq partial
    #pragma unroll
    for (int o = 32; o > 0; o >>= 1) ssq += __shfl_down(ssq, o, 64);
    if (lane == 0) partial[b * HC + cr] = ssq;
}

// ---------------- norm kernel: FOUR blocks (256 thr) per image -------------
__global__ __launch_bounds__(256) void hog_norm_kernel(
    float* __restrict__ out, const float* __restrict__ partial)
{
    const int bq = blockIdx.x, tid = threadIdx.x;
    const int b = bq >> 2, q = bq & 3;
    __shared__ float wsum[4];
    __shared__ float s_inv;
    float s = (tid < HC) ? partial[b * HC + tid] : 0.f;   // lanes 0..27, wave 0
    #pragma unroll
    for (int o = 32; o > 0; o >>= 1) s += __shfl_down(s, o, 64);
    if ((tid & 63) == 0) wsum[tid >> 6] = s;
    __syncthreads();
    if (tid == 0) {
        float t = wsum[0] + wsum[1] + wsum[2] + wsum[3];
        s_inv = 1.0f / (sqrtf(t) + 1e-6f);
    }
    __syncthreads();
    float inv = s_inv;
    float4* o4 = (float4*)(out + (size_t)b * OUTPER + (size_t)q * (OUTPER / 4));
    for (int i = tid; i < OUTPER / 16; i += 256) {   // 392 float4 per quarter
        float4 w = o4[i];
        w.x *= inv; w.y *= inv; w.z *= inv; w.w *= inv;
        o4[i] = w;
    }
}

extern "C" void kernel_launch(void* const* d_in, const int* in_sizes, int n_in,
                              void* d_out, int out_size, void* d_ws, size_t ws_size,
                              hipStream_t stream) {
    const float* x     = (const float*)d_in[0];
    const float* gauss = (const float*)d_in[1];   // unused: separable constants inlined
    // d_in[2]=kx, d_in[3]=ky: compile-time Sobel constants (hardcoded)
    float* out     = (float*)d_out;
    float* partial = (float*)d_ws;       // 7168 floats, fully overwritten

    hog_main_kernel<<<BATCH * 7, 256, 0, stream>>>(x, gauss, out, partial);
    hog_norm_kernel<<<BATCH * 4, 256, 0, stream>>>(out, partial);
}